// Round 6
// baseline (157.174 us; speedup 1.0000x reference)
//
#include <hip/hip_runtime.h>
#include <hip/hip_bf16.h>
#include <stdint.h>

#define TT 4096
#define DM 128
#define DIN 256
#define NB 4

typedef __attribute__((ext_vector_type(4))) float f32x4;
typedef __attribute__((ext_vector_type(8))) short s16x8;
typedef __attribute__((ext_vector_type(4))) short s16x4;

__device__ __forceinline__ unsigned short f2bf(float f) {
    union { float f; unsigned int u; } v; v.f = f;
    return (unsigned short)((v.u + 0x7FFFu + ((v.u >> 16) & 1u)) >> 16);
}
__device__ __forceinline__ float bf2f(unsigned short h) {
    union { unsigned int u; float f; } v; v.u = ((unsigned int)h) << 16;
    return v.f;
}

// async global->LDS, 16B/lane, dest = wave-uniform base + lane*16
__device__ __forceinline__ void cp16(const void* g, void* l) {
    __builtin_amdgcn_global_load_lds(
        (__attribute__((address_space(1))) unsigned int*)(size_t)g,
        (__attribute__((address_space(3))) unsigned int*)l, 16, 0, 0);
}

// ---------------- kernel 0: W (256x128 f32) -> Wt bf16 [3][128][256] ----------------
__global__ __launch_bounds__(256) void k_wt(const float* __restrict__ Wq,
                                            const float* __restrict__ Wk,
                                            const float* __restrict__ Wv,
                                            unsigned short* __restrict__ Wtb) {
    int tid = blockIdx.x * 256 + threadIdx.x;
    int m = tid >> 15;
    int r = tid & 32767;
    int n = r >> 8;
    int k = r & 255;
    const float* W = (m == 0) ? Wq : (m == 1) ? Wk : Wv;
    Wtb[(size_t)tid] = f2bf(W[k * DM + n]);
}

// ---------------- kernel 1: projections x@W+b -> Q/K/V bf16 [16384][128] ------------
__global__ __launch_bounds__(256) void k_proj(const float* __restrict__ x,
        const float* __restrict__ bq, const float* __restrict__ bk, const float* __restrict__ bv,
        const unsigned short* __restrict__ Wtb,
        unsigned short* __restrict__ Qb, unsigned short* __restrict__ Kb,
        unsigned short* __restrict__ Vb) {
    __shared__ __align__(16) unsigned short wt[DM][40];
    __shared__ __align__(16) unsigned short xl[64][40];
    int m = blockIdx.x >> 8;
    int tile = blockIdx.x & 255;
    int rowbase = tile * 64;
    int i = threadIdx.x;
    int w = i >> 6, l = i & 63;
    int lg = l >> 4, ll = l & 15;
    const float* bias = (m == 0) ? bq : (m == 1) ? bk : bv;
    unsigned short* out = (m == 0) ? Qb : (m == 1) ? Kb : Vb;
    const unsigned short* wsrc = Wtb + (size_t)m * DM * DIN;

    f32x4 acc[8];
    for (int n = 0; n < 8; n++) acc[n] = (f32x4){0.f, 0.f, 0.f, 0.f};

    for (int kk = 0; kk < 8; kk++) {
        int k0 = kk * 32;
        for (int t = 0; t < 2; t++) {
            int idx = i + t * 256;
            int row = idx >> 2, c8 = idx & 3;
            s16x8 v = *(const s16x8*)(wsrc + (size_t)row * DIN + k0 + c8 * 8);
            *(s16x8*)(&wt[row][c8 * 8]) = v;
        }
        for (int t = 0; t < 2; t++) {
            int idx = i + t * 256;
            int row = idx >> 3, c4 = idx & 7;
            f32x4 v = *(const f32x4*)(x + (size_t)(rowbase + row) * DIN + k0 + c4 * 4);
            s16x4 h;
            for (int j = 0; j < 4; j++) h[j] = (short)f2bf(v[j]);
            *(s16x4*)(&xl[row][c4 * 4]) = h;
        }
        __syncthreads();
        s16x8 a = *(const s16x8*)(&xl[w * 16 + ll][lg * 8]);
        for (int n = 0; n < 8; n++) {
            s16x8 b = *(const s16x8*)(&wt[n * 16 + ll][lg * 8]);
            acc[n] = __builtin_amdgcn_mfma_f32_16x16x32_bf16(a, b, acc[n], 0, 0, 0);
        }
        __syncthreads();
    }
    for (int n = 0; n < 8; n++) {
        int col = n * 16 + ll;
        float bv_ = bias[col];
        for (int j = 0; j < 4; j++) {
            int row = rowbase + w * 16 + lg * 4 + j;
            out[(size_t)row * DM + col] = f2bf(acc[n][j] + bv_);
        }
    }
}

// ---------------- kernel 2: V [b][t][d] -> Vt [b][d][t] (bf16) ----------------------
__global__ __launch_bounds__(256) void k_vt(const unsigned short* __restrict__ Vb,
                                            unsigned short* __restrict__ Vtb) {
    __shared__ __align__(16) unsigned short tile[64][72];
    int bid = blockIdx.x;
    int b = bid >> 7;
    int rem = bid & 127;
    int tI = rem >> 1, dI = rem & 1;
    int t0 = tI * 64, d0 = dI * 64;
    int i = threadIdx.x;
    for (int t = 0; t < 2; t++) {
        int idx = i + t * 256;
        int r = idx >> 3, c8 = idx & 7;
        s16x8 v = *(const s16x8*)(Vb + ((size_t)(b * TT) + t0 + r) * DM + d0 + c8 * 8);
        *(s16x8*)(&tile[r][c8 * 8]) = v;
    }
    __syncthreads();
    for (int t = 0; t < 2; t++) {
        int idx = i + t * 256;
        int r2 = idx >> 3, c8 = idx & 7;
        s16x8 v;
        for (int j = 0; j < 8; j++) v[j] = (short)tile[c8 * 8 + j][r2];
        *(s16x8*)(Vtb + ((size_t)b * DM + d0 + r2) * TT + t0 + c8 * 8) = v;
    }
}

// ---------------- kernel A: rowsums of exp(S), key-split ----------------------------
// grid 2048 = 4 b x 128 rowtiles x 4 kq; block 256 = 4 waves (rg=w&1, ks=w>>1).
// Each block: 32 rows x 1024 keys, 32-key tiles, ring-3 LDS, depth-2 prefetch.
// Output: rsum8[b][kq*2+ks][4096] f32 partials (deterministic, no atomics).
__global__ __launch_bounds__(256, 4) void k_rowsum(const unsigned short* __restrict__ Qb,
        const unsigned short* __restrict__ Kb, float* __restrict__ rsum8) {
    __shared__ __align__(16) char smem[24576];   // 3 x 8KB K slots

    int bid = blockIdx.x;
    int id2 = (bid & 7) * 256 + (bid >> 3);     // XCD swizzle (2048%8==0)
    int b = id2 >> 9;
    int rem = id2 & 511;
    int rt = rem >> 2, kq = rem & 3;
    int rowbase = rt * 32;
    int i = threadIdx.x;
    int w = i >> 6, l = i & 63;
    int rg = w & 1, ks = w >> 1;
    int lg = l >> 4, ll = l & 15;

    const unsigned short* Qrow = Qb + ((size_t)(b * TT) + rowbase) * DM;
    const unsigned short* Krow = Kb + (size_t)(b * TT) * DM + (size_t)(kq * 1024) * DM;
    const float scale = 0.08838834764831845f;

    s16x8 qf[4];
    for (int c = 0; c < 4; c++)
        qf[c] = *(const s16x8*)(Qrow + (size_t)(rg * 16 + ll) * DM + c * 32 + lg * 8);

    int kr = ks * 16 + ll;
    // stage: 8KB = 8 chunks of 1KB (4 rows x 256B); wave w does chunks w, w+4
    auto stage = [&](char* kbuf, int t) {
        int s0 = t * 32;
        for (int u = 0; u < 2; u++) {
            int c = u * 4 + w;
            int row = c * 4 + (l >> 4);
            int g = (l & 15) ^ (row & 7);
            cp16(Krow + (size_t)(s0 + row) * DM + g * 8, kbuf + c * 1024);
        }
    };

    float rs[4] = {0.f, 0.f, 0.f, 0.f};
    stage(smem, 0);
    stage(smem + 8192, 1);
    asm volatile("s_waitcnt vmcnt(2)" ::: "memory");
    __builtin_amdgcn_s_barrier();

    int cur = 0, nxt = 2;
    for (int t = 0; t < 32; t++) {
        int tn = (t + 2 <= 31) ? t + 2 : 31;
        stage(smem + nxt * 8192, tn);
        const char* kbase = smem + cur * 8192 + kr * 256;
        f32x4 a0 = (f32x4){0.f, 0.f, 0.f, 0.f}, a1 = (f32x4){0.f, 0.f, 0.f, 0.f};
        {
            s16x8 k0 = *(const s16x8*)(kbase + (((0 * 4 + lg) ^ (kr & 7)) << 4));
            s16x8 k1 = *(const s16x8*)(kbase + (((1 * 4 + lg) ^ (kr & 7)) << 4));
            s16x8 k2 = *(const s16x8*)(kbase + (((2 * 4 + lg) ^ (kr & 7)) << 4));
            s16x8 k3 = *(const s16x8*)(kbase + (((3 * 4 + lg) ^ (kr & 7)) << 4));
            a0 = __builtin_amdgcn_mfma_f32_16x16x32_bf16(qf[0], k0, a0, 0, 0, 0);
            a1 = __builtin_amdgcn_mfma_f32_16x16x32_bf16(qf[1], k1, a1, 0, 0, 0);
            a0 = __builtin_amdgcn_mfma_f32_16x16x32_bf16(qf[2], k2, a0, 0, 0, 0);
            a1 = __builtin_amdgcn_mfma_f32_16x16x32_bf16(qf[3], k3, a1, 0, 0, 0);
        }
        f32x4 acc;
        for (int j = 0; j < 4; j++) acc[j] = a0[j] + a1[j];
        for (int j = 0; j < 4; j++) rs[j] += __expf(acc[j] * scale);
        asm volatile("s_waitcnt vmcnt(2)" ::: "memory");
        __builtin_amdgcn_s_barrier();
        cur++; if (cur == 3) cur = 0;
        nxt++; if (nxt == 3) nxt = 0;
    }
    // reduce over the 16 key-lanes
    for (int mm = 1; mm < 16; mm <<= 1)
        for (int j = 0; j < 4; j++) rs[j] += __shfl_xor(rs[j], mm, 64);
    if (ll == 0) {
        int p = kq * 2 + ks;
        float* dst = rsum8 + ((size_t)(b * 8 + p)) * TT + rowbase + rg * 16 + lg * 4;
        for (int j = 0; j < 4; j++) dst[j] = rs[j];
    }
}

// wait: QK here accumulated a0 over chunks 0,2 and a1 over 1,3 then added — matches
// a plain sum over c (fp32 add order differs from kernel B's chain; harmless, rowsum
// is only used as a normalizer).

// ---------------- kernel B: attn write + O = P@V, ring-4 depth-3 --------------------
// grid 512 (4 b x 128 rowtiles of 32), block 256 = 4 waves (rg=w&1, ks=w>>1).
// 32-key tiles, 128 iters; slot = K[32][256B] + V[128][64B] (16KB), ring of 4.
// One s_barrier/iter, counted vmcnt(9): stage(t+1) drained, stores get >=1 iter.
__global__ __launch_bounds__(256, 2) void k_attn(const unsigned short* __restrict__ Qb,
        const unsigned short* __restrict__ Kb, const unsigned short* __restrict__ Vtb,
        const float* __restrict__ rsum8,
        float* __restrict__ outO, float* __restrict__ outA) {
    __shared__ __align__(16) char smem[70656];
    // ring: 4 x 16KB at 0; Pw: 65536 + w*1280 ([16][40] u16); obuf aliases ring at end

    int bid = blockIdx.x;
    int id2 = (bid & 7) * 64 + (bid >> 3);   // XCD swizzle (512%8==0)
    int b = id2 >> 7;
    int rowbase = (id2 & 127) * 32;
    int i = threadIdx.x;
    int w = i >> 6, l = i & 63;
    int rg = w & 1, ks = w >> 1;
    int lg = l >> 4, ll = l & 15;

    const unsigned short* Qrow = Qb + ((size_t)(b * TT) + rowbase) * DM;
    const unsigned short* Krow = Kb + (size_t)(b * TT) * DM;
    const unsigned short* Vt_b = Vtb + (size_t)b * DM * TT;
    const float scale = 0.08838834764831845f;

    unsigned short* Pw = (unsigned short*)(smem + 65536 + w * 1280);

    s16x8 qf[4];
    for (int c = 0; c < 4; c++)
        qf[c] = *(const s16x8*)(Qrow + (size_t)(rg * 16 + ll) * DM + c * 32 + lg * 8);

    // inv from 8 partial rowsums
    float inv_[4];
    for (int j = 0; j < 4; j++) {
        int row = rowbase + rg * 16 + lg * 4 + j;
        float s = 0.f;
        for (int p = 0; p < 8; p++) s += rsum8[((size_t)(b * 8 + p)) * TT + row];
        inv_[j] = 1.0f / s;
    }

    int kr = ks * 16 + ll;
    auto stage = [&](char* slot, int t) {
        int s0 = t * 32;
        // K: 8KB, 8 chunks (4 rows x 256B); wave w: chunks w, w+4
        for (int u = 0; u < 2; u++) {
            int c = u * 4 + w;
            int row = c * 4 + (l >> 4);
            int g = (l & 15) ^ (row & 7);
            cp16(Krow + (size_t)(s0 + row) * DM + g * 8, slot + c * 1024);
        }
        // V: 8KB at +8192, 8 chunks (16 rows x 64B); wave w: chunks w, w+4
        for (int u = 0; u < 2; u++) {
            int c = u * 4 + w;
            int row = c * 16 + (l >> 2);
            int g = (l & 3) ^ (row & 3);
            cp16(Vt_b + (size_t)row * TT + s0 + g * 8, slot + 8192 + c * 1024);
        }
    };

    // zero-pad Pw cols 16..31 once (PV A-frag k=16..31 multiplies zeros)
    for (int j = 0; j < 4; j++) Pw[(lg * 4 + j) * 40 + 16 + ll] = 0;
    f32x4 oacc[8];
    for (int n = 0; n < 8; n++) oacc[n] = (f32x4){0.f, 0.f, 0.f, 0.f};

    stage(smem, 0);
    stage(smem + 16384, 1);
    stage(smem + 32768, 2);
    asm volatile("s_waitcnt vmcnt(8)" ::: "memory");
    __builtin_amdgcn_s_barrier();

    for (int t = 0; t < 128; t++) {
        int s0 = t * 32;
        int tn = (t + 3 <= 127) ? t + 3 : 127;
        stage(smem + ((t + 3) & 3) * 16384, tn);

        const char* kbase = smem + (t & 3) * 16384 + kr * 256;
        f32x4 a0 = (f32x4){0.f, 0.f, 0.f, 0.f}, a1 = (f32x4){0.f, 0.f, 0.f, 0.f};
        {
            s16x8 k0 = *(const s16x8*)(kbase + (((0 * 4 + lg) ^ (kr & 7)) << 4));
            s16x8 k1 = *(const s16x8*)(kbase + (((1 * 4 + lg) ^ (kr & 7)) << 4));
            s16x8 k2 = *(const s16x8*)(kbase + (((2 * 4 + lg) ^ (kr & 7)) << 4));
            s16x8 k3 = *(const s16x8*)(kbase + (((3 * 4 + lg) ^ (kr & 7)) << 4));
            a0 = __builtin_amdgcn_mfma_f32_16x16x32_bf16(qf[0], k0, a0, 0, 0, 0);
            a1 = __builtin_amdgcn_mfma_f32_16x16x32_bf16(qf[1], k1, a1, 0, 0, 0);
            a0 = __builtin_amdgcn_mfma_f32_16x16x32_bf16(qf[2], k2, a0, 0, 0, 0);
            a1 = __builtin_amdgcn_mfma_f32_16x16x32_bf16(qf[3], k3, a1, 0, 0, 0);
        }
        for (int j = 0; j < 4; j++) {
            float p = __expf((a0[j] + a1[j]) * scale) * inv_[j];
            Pw[(lg * 4 + j) * 40 + ll] = f2bf(p);
        }
        asm volatile("s_waitcnt lgkmcnt(0)" ::: "memory");
        __builtin_amdgcn_sched_barrier(0);
        // PV: A = P rows (this wave's 16 rows) x k=32 (16 real + 16 zero)
        {
            s16x8 paf = *(const s16x8*)(Pw + ll * 40 + lg * 8);
            const char* vbuf = smem + (t & 3) * 16384 + 8192;
            int gl = ks * 2 + (lg & 1);
            for (int n8 = 0; n8 < 8; n8++) {
                int row = n8 * 16 + ll;
                s16x8 bfr = *(const s16x8*)(vbuf + row * 64 + ((gl ^ (row & 3)) << 4));
                oacc[n8] = __builtin_amdgcn_mfma_f32_16x16x32_bf16(paf, bfr, oacc[n8], 0, 0, 0);
            }
        }
        // attn store: wave's [16 rows][16 keys] slice, 16B/lane, nontemporal
        {
            int arow = l >> 2, acol = (l & 3) * 4;
            s16x4 pv = *(const s16x4*)(Pw + arow * 40 + acol);
            f32x4 fv;
            for (int q = 0; q < 4; q++) fv[q] = bf2f((unsigned short)pv[q]);
            __builtin_nontemporal_store(fv,
                (f32x4*)(outA + ((size_t)(b * TT) + rowbase + rg * 16 + arow) * TT
                         + s0 + ks * 16 + acol));
        }
        asm volatile("s_waitcnt vmcnt(9)" ::: "memory");
        __builtin_amdgcn_s_barrier();
    }

    // ---- tail: O reduction across ks pairs, then cooperative store ----
    asm volatile("s_waitcnt vmcnt(0)" ::: "memory");
    __builtin_amdgcn_s_barrier();
    float* obuf = (float*)smem;   // [2 rg][16][132]
    if (ks == 1) {
        float* dst = obuf + (size_t)rg * 2112;
        for (int n8 = 0; n8 < 8; n8++)
            for (int j = 0; j < 4; j++)
                dst[(lg * 4 + j) * 132 + n8 * 16 + ll] = oacc[n8][j];
    }
    __syncthreads();
    if (ks == 0) {
        float* dst = obuf + (size_t)rg * 2112;
        for (int n8 = 0; n8 < 8; n8++)
            for (int j = 0; j < 4; j++) {
                int idx = (lg * 4 + j) * 132 + n8 * 16 + ll;
                dst[idx] += oacc[n8][j];
            }
    }
    __syncthreads();
    {
        int row = i >> 3;            // 0..31
        int colf = (i & 7) * 16;     // 0..112
        const float* src = obuf + (size_t)(row >> 4) * 2112 + (row & 15) * 132 + colf;
        float* dst = outO + ((size_t)(b * TT) + rowbase + row) * DM + colf;
        for (int u = 0; u < 4; u++)
            *(f32x4*)(dst + u * 4) = *(const f32x4*)(src + u * 4);
    }
}

extern "C" void kernel_launch(void* const* d_in, const int* in_sizes, int n_in,
                              void* d_out, int out_size, void* d_ws, size_t ws_size,
                              hipStream_t stream) {
    const float* x  = (const float*)d_in[0];
    const float* Wq = (const float*)d_in[1];
    const float* bq = (const float*)d_in[2];
    const float* Wk = (const float*)d_in[3];
    const float* bk = (const float*)d_in[4];
    const float* Wv = (const float*)d_in[5];
    const float* bv = (const float*)d_in[6];
    float* outO = (float*)d_out;
    float* outA = outO + (size_t)NB * TT * DM;

    char* ws = (char*)d_ws;
    unsigned short* Qb  = (unsigned short*)(ws);
    unsigned short* Kb  = (unsigned short*)(ws + ((size_t)1 << 22));
    unsigned short* Vb  = (unsigned short*)(ws + ((size_t)2 << 22));
    unsigned short* Vtb = (unsigned short*)(ws + ((size_t)3 << 22));
    unsigned short* Wtb = (unsigned short*)(ws + ((size_t)4 << 22));
    float* rsum8 = (float*)(ws + ((size_t)2 << 22));   // aliases Vb (dead after k_vt)

    k_wt<<<dim3(384), dim3(256), 0, stream>>>(Wq, Wk, Wv, Wtb);
    k_proj<<<dim3(768), dim3(256), 0, stream>>>(x, bq, bk, bv, Wtb, Qb, Kb, Vb);
    k_vt<<<dim3(512), dim3(256), 0, stream>>>(Vb, Vtb);
    k_rowsum<<<dim3(2048), dim3(256), 0, stream>>>(Qb, Kb, rsum8);
    k_attn<<<dim3(512), dim3(256), 0, stream>>>(Qb, Kb, Vtb, rsum8, outO, outA);
}